// Round 1
// baseline (187.903 us; speedup 1.0000x reference)
//
#include <hip/hip_runtime.h>

// Problem shape (fixed by the reference): B=128, D=1024.
// d_in[0] = h_mean [B,D] f32, d_in[1] = h_cov [B,D,D] f32.
// d_out   = a_mean [B*D] f32 ++ a_cov [B*D*D] f32 (tuple concatenated flat).

#define DDIM 1024

__device__ __forceinline__ float gelu_cdf(float x) {
    // Phi(x) = 0.5*(1+erf(x/sqrt(2))) — exact erf formulation (approximate=False)
    return 0.5f * (1.0f + erff(x * 0.70710678118654752440f));
}

__device__ __forceinline__ float gelu_grad(float x) {
    // g'(x) = Phi(x) + x * phi(x),  phi(x) = exp(-x^2/2)/sqrt(2*pi)
    return gelu_cdf(x) + x * 0.39894228040143267794f * expf(-0.5f * x * x);
}

// Kernel A: a_mean = x*Phi(x); nabla = g'(x). One element per thread.
__global__ void mean_nabla_kernel(const float* __restrict__ h_mean,
                                  float* __restrict__ a_mean,
                                  float* __restrict__ nabla, int n) {
    int i = blockIdx.x * blockDim.x + threadIdx.x;
    if (i >= n) return;
    float x = h_mean[i];
    float cdf = gelu_cdf(x);
    a_mean[i] = x * cdf;
    nabla[i] = cdf + x * 0.39894228040143267794f * expf(-0.5f * x * x);
}

// Kernel B: one block per (n,i) row of h_cov; 256 threads x float4 = 1024 cols.
// a_cov[n,i,l] = nabla[n,i] * h_cov[n,i,l] * nabla[n,l]
__global__ void __launch_bounds__(256) sandwich_kernel(
        const float* __restrict__ h_cov,
        const float* __restrict__ nabla,
        float* __restrict__ a_cov) {
    const int row = blockIdx.x;            // row = n*D + i, 0..B*D-1
    const int n = row >> 10;               // / DDIM
    const float s = nabla[row];            // nabla[n,i] (L1-broadcast)
    const size_t base = (size_t)row * DDIM;
    const float4 c  = ((const float4*)(h_cov + base))[threadIdx.x];
    const float4 nl = ((const float4*)(nabla + (size_t)n * DDIM))[threadIdx.x];
    float4 r;
    r.x = s * c.x * nl.x;
    r.y = s * c.y * nl.y;
    r.z = s * c.z * nl.z;
    r.w = s * c.w * nl.w;
    ((float4*)(a_cov + base))[threadIdx.x] = r;
}

// Fallback (only if ws_size is too small): a_mean only.
__global__ void mean_only_kernel(const float* __restrict__ h_mean,
                                 float* __restrict__ a_mean, int n) {
    int i = blockIdx.x * blockDim.x + threadIdx.x;
    if (i >= n) return;
    float x = h_mean[i];
    a_mean[i] = x * gelu_cdf(x);
}

// Fallback sandwich: recompute g' inline (5 transcendental pairs / thread).
__global__ void __launch_bounds__(256) sandwich_fused_kernel(
        const float* __restrict__ h_cov,
        const float* __restrict__ h_mean,
        float* __restrict__ a_cov) {
    const int row = blockIdx.x;
    const int n = row >> 10;
    const float s = gelu_grad(h_mean[row]);
    const size_t base = (size_t)row * DDIM;
    const float4 c  = ((const float4*)(h_cov + base))[threadIdx.x];
    const float4 hm = ((const float4*)(h_mean + (size_t)n * DDIM))[threadIdx.x];
    float4 r;
    r.x = s * c.x * gelu_grad(hm.x);
    r.y = s * c.y * gelu_grad(hm.y);
    r.z = s * c.z * gelu_grad(hm.z);
    r.w = s * c.w * gelu_grad(hm.w);
    ((float4*)(a_cov + base))[threadIdx.x] = r;
}

extern "C" void kernel_launch(void* const* d_in, const int* in_sizes, int n_in,
                              void* d_out, int out_size, void* d_ws, size_t ws_size,
                              hipStream_t stream) {
    const float* h_mean = (const float*)d_in[0];
    const float* h_cov  = (const float*)d_in[1];
    float* out = (float*)d_out;

    const int BD = in_sizes[0];       // B*D = 131072
    float* a_mean = out;              // first BD floats
    float* a_cov  = out + BD;         // next BD*D floats

    if (ws_size >= (size_t)BD * sizeof(float)) {
        float* nabla = (float*)d_ws;
        mean_nabla_kernel<<<(BD + 255) / 256, 256, 0, stream>>>(h_mean, a_mean, nabla, BD);
        sandwich_kernel<<<BD, 256, 0, stream>>>(h_cov, nabla, a_cov);
    } else {
        mean_only_kernel<<<(BD + 255) / 256, 256, 0, stream>>>(h_mean, a_mean, BD);
        sandwich_fused_kernel<<<BD, 256, 0, stream>>>(h_cov, h_mean, a_cov);
    }
}